// Round 4
// baseline (764.891 us; speedup 1.0000x reference)
//
#include <hip/hip_runtime.h>
#include <stdint.h>

typedef unsigned short u16;
typedef __attribute__((ext_vector_type(8))) short short8;
typedef __attribute__((ext_vector_type(4))) float f32x4;

#define N_NODES 100000
#define RREL    3
#define NEDGE   1600000
#define NPAIR   1024
#define NSEG    (RREL * N_NODES)

// ---------- bf16 helpers ----------
__device__ __forceinline__ float bf2f(u16 h) {
    union { unsigned int u; float f; } c; c.u = ((unsigned int)h) << 16; return c.f;
}
__device__ __forceinline__ u16 f2bf(float f) {
    union { float f; unsigned int u; } c; c.f = f;
    unsigned int u = c.u;
    u += 0x7fffu + ((u >> 16) & 1u);   // round-to-nearest-even
    return (u16)(u >> 16);
}

// ---------- zero ints ----------
__global__ __launch_bounds__(256) void zero_kernel(int* __restrict__ cnt, int* __restrict__ gcur) {
    int i = blockIdx.x * 256 + threadIdx.x;
    if (i < NSEG) cnt[i] = 0;
    if (i == 0) *gcur = 0;
}

// ---------- cast f32 -> bf16, 4 elems/thread ----------
__global__ __launch_bounds__(256) void cast_kernel(const float* __restrict__ in,
                                                   u16* __restrict__ out, int n4) {
    int i = blockIdx.x * 256 + threadIdx.x;
    if (i >= n4) return;
    float4 v = ((const float4*)in)[i];
    uint2 o;
    o.x = ((unsigned int)f2bf(v.y) << 16) | (unsigned int)f2bf(v.x);
    o.y = ((unsigned int)f2bf(v.w) << 16) | (unsigned int)f2bf(v.z);
    ((uint2*)out)[i] = o;
}

// ---------- CSR build ----------
__global__ __launch_bounds__(256) void hist_kernel(const int* __restrict__ et,
                                                   const int* __restrict__ ed,
                                                   int* __restrict__ cnt) {
    int e = blockIdx.x * 256 + threadIdx.x;
    if (e < NEDGE) atomicAdd(&cnt[et[e] * N_NODES + ed[e]], 1);
}

// order-free contiguous slot allocation: wave-scan + one atomic per wave
__global__ __launch_bounds__(256) void alloc_seg(const int* __restrict__ cnt,
                                                 int* __restrict__ seg_start,
                                                 int* __restrict__ seg_cur,
                                                 int* __restrict__ gcur) {
    int t = blockIdx.x * 256 + threadIdx.x;   // handles 4 segments
    int i0 = t * 4;
    int c0 = 0, c1 = 0, c2 = 0, c3 = 0;
    if (i0 < NSEG) {
        const int4* c4 = (const int4*)cnt;
        int4 v = c4[t];
        c0 = v.x; c1 = v.y; c2 = v.z; c3 = v.w;
    }
    int s = c0 + c1 + c2 + c3;
    int pre = s;
    #pragma unroll
    for (int d = 1; d < 64; d <<= 1) {
        int v = __shfl_up(pre, d);
        if ((threadIdx.x & 63) >= d) pre += v;
    }
    int excl  = pre - s;
    int total = __shfl(pre, 63);
    int base  = 0;
    if ((threadIdx.x & 63) == 63) base = atomicAdd(gcur, total);
    base = __shfl(base, 63);
    if (i0 < NSEG) {
        int run = base + excl;
        seg_start[i0 + 0] = run; seg_cur[i0 + 0] = run; run += c0;
        seg_start[i0 + 1] = run; seg_cur[i0 + 1] = run; run += c1;
        seg_start[i0 + 2] = run; seg_cur[i0 + 2] = run; run += c2;
        seg_start[i0 + 3] = run; seg_cur[i0 + 3] = run;
    }
}

__global__ __launch_bounds__(256) void scatter_kernel(const int* __restrict__ es,
                                                      const int* __restrict__ ed,
                                                      const int* __restrict__ et,
                                                      int* __restrict__ seg_cur,
                                                      int* __restrict__ sorted_src) {
    int e = blockIdx.x * 256 + threadIdx.x;
    if (e < NEDGE) {
        int sgi = et[e] * N_NODES + ed[e];
        int p = atomicAdd(&seg_cur[sgi], 1);
        if ((unsigned)p < (unsigned)NEDGE) sorted_src[p] = es[e];
    }
}

// ---------- per-segment mean of 128-wide rows; one wave per (r,dst) ----------
// F32IN: X is float (N,128). else: X is bf16 (N,128).
// writes Abuf as (N, 384) bf16: row dst, cols [r*128, r*128+128)
template <bool F32IN>
__global__ __launch_bounds__(256) void seg_mean(const void* __restrict__ Xv,
                                                const int* __restrict__ seg_start,
                                                const int* __restrict__ cnt,
                                                const int* __restrict__ sorted_src,
                                                u16* __restrict__ Abuf) {
    int wid  = (blockIdx.x * 256 + threadIdx.x) >> 6;
    int lane = threadIdx.x & 63;
    if (wid >= NSEG) return;
    int r   = wid / N_NODES;
    int dst = wid - r * N_NODES;
    int c  = cnt[wid];
    int st = seg_start[wid];
    float a0 = 0.f, a1 = 0.f;
    for (int e = 0; e < c; ++e) {
        int src = sorted_src[st + e];
        if ((unsigned)src >= (unsigned)N_NODES) src = 0;   // defensive
        if (F32IN) {
            float2 v = ((const float2*)Xv)[(size_t)src * 64 + lane];
            a0 += v.x; a1 += v.y;
        } else {
            unsigned int v = ((const unsigned int*)Xv)[(size_t)src * 64 + lane];
            a0 += bf2f((u16)(v & 0xffffu));
            a1 += bf2f((u16)(v >> 16));
        }
    }
    float sc = 1.0f / (float)(c > 0 ? c : 1);
    unsigned int o = ((unsigned int)f2bf(a1 * sc) << 16) | (unsigned int)f2bf(a0 * sc);
    ((unsigned int*)Abuf)[(size_t)dst * 192 + r * 64 + lane] = o;
}

// ---------- weight transpose: f32 (512 x BN) k-major -> bf16 Wt (BN x 512) n-major ----------
template <int BN>
__global__ __launch_bounds__(256) void transpose_w(const float* __restrict__ Wrel,
                                                   const float* __restrict__ Wroot,
                                                   u16* __restrict__ Wt) {
    int idx = blockIdx.x * 256 + threadIdx.x;
    if (idx >= BN * 512) return;
    int n = idx >> 9;
    int k = idx & 511;
    float v = (k < 384) ? Wrel[(size_t)k * BN + n] : Wroot[(size_t)(k - 384) * BN + n];
    Wt[idx] = f2bf(v);
}

// ---------- fused GEMM: Out(M,BN) = [Alo(M,384) | Ahi(M,128)]_bf16 @ Wt^T + bias ----------
template <int BN, bool RELU, bool OUTF32>
__global__ __launch_bounds__(256) void gemm_fused(const u16* __restrict__ Alo,
                                                  const u16* __restrict__ Ahi,
                                                  const u16* __restrict__ Wt,
                                                  const float* __restrict__ bias,
                                                  void* __restrict__ OutV) {
    constexpr int M = N_NODES;
    constexpr int BM = 128, BK = 32, KTOT = 512, KLO = 384;
    __shared__ __align__(16) u16 As[BM * BK];
    __shared__ __align__(16) u16 Bs[BN * BK];
    const int t = threadIdx.x;
    const int w = t >> 6, l = t & 63;
    const int bm = blockIdx.x * BM;
    constexpr int WN  = (BN == 128) ? 2 : 1;
    constexpr int WTM = (BN == 128) ? 64 : 32;
    constexpr int WTN = 64;
    constexpr int MI = WTM / 16, NI = WTN / 16;
    const int wm = w / WN, wn = w % WN;
    const int q = l >> 4, lm = l & 15;   // quad, intra-16 index

    f32x4 acc[MI][NI] = {};

    const int ar = t >> 2;            // 0..63
    const int ac = (t & 3) * 8;       // 0,8,16,24

    for (int kt = 0; kt < KTOT / BK; ++kt) {
        const int k0 = kt * BK;
        // ---- load tile into registers (global, 16B vector loads) ----
        const u16* base; int stride, kk;
        if (k0 < KLO) { base = Alo; stride = 384; kk = k0; }
        else          { base = Ahi; stride = 128; kk = k0 - KLO; }
        short8 va[2];
        #pragma unroll
        for (int i = 0; i < 2; ++i) {
            int gr = bm + i * 64 + ar; if (gr >= M) gr = M - 1;
            va[i] = *(const short8*)(base + (size_t)gr * stride + kk + ac);
        }
        short8 vb[BN / 64];
        #pragma unroll
        for (int i = 0; i < BN / 64; ++i) {
            int rn = i * 64 + ar;
            vb[i] = *(const short8*)(Wt + (size_t)rn * KTOT + k0 + ac);
        }
        // ---- store to LDS ----
        __syncthreads();   // previous iteration done reading LDS
        #pragma unroll
        for (int i = 0; i < 2; ++i)
            *(short8*)&As[(i * 64 + ar) * BK + ac] = va[i];
        #pragma unroll
        for (int i = 0; i < BN / 64; ++i)
            *(short8*)&Bs[(i * 64 + ar) * BK + ac] = vb[i];
        __syncthreads();
        // ---- one MFMA per (mi,ni) covers the whole K=32 tile ----
        // A-frag: lane holds A[m = lane&15][k = (lane>>4)*8 + j], j=0..7
        short8 fa[MI], fb[NI];
        #pragma unroll
        for (int mi = 0; mi < MI; ++mi)
            fa[mi] = *(const short8*)&As[(wm * WTM + mi * 16 + lm) * BK + q * 8];
        #pragma unroll
        for (int ni = 0; ni < NI; ++ni)
            fb[ni] = *(const short8*)&Bs[(wn * WTN + ni * 16 + lm) * BK + q * 8];
        #pragma unroll
        for (int mi = 0; mi < MI; ++mi)
            #pragma unroll
            for (int ni = 0; ni < NI; ++ni)
                acc[mi][ni] = __builtin_amdgcn_mfma_f32_16x16x32_bf16(
                    fa[mi], fb[ni], acc[mi][ni], 0, 0, 0);
    }
    // epilogue: C/D layout col=lane&15, row=q*4+reg
    #pragma unroll
    for (int mi = 0; mi < MI; ++mi) {
        #pragma unroll
        for (int ni = 0; ni < NI; ++ni) {
            int gc = wn * WTN + ni * 16 + lm;
            float bv = bias[gc];
            #pragma unroll
            for (int rg = 0; rg < 4; ++rg) {
                int gr = bm + wm * WTM + mi * 16 + q * 4 + rg;
                if (gr < M) {
                    float v = acc[mi][ni][rg] + bv;
                    if (RELU) v = fmaxf(v, 0.0f);
                    if (OUTF32) ((float*)OutV)[(size_t)gr * BN + gc] = v;
                    else        ((u16*)OutV)[(size_t)gr * BN + gc] = f2bf(v);
                }
            }
        }
    }
}

// ---------- final pair MLP: tanh(concat(node[nest],node[food]) @ fcW + fcb), all f32 ----------
__global__ __launch_bounds__(128) void pair_mlp(const float* __restrict__ node,
                                                const int* __restrict__ nest,
                                                const int* __restrict__ food,
                                                const float* __restrict__ fcW,
                                                const float* __restrict__ fcb,
                                                float* __restrict__ out) {
    int p = blockIdx.x;
    int t = threadIdx.x;
    __shared__ float pv[128];
    int n0 = nest[p], n1 = food[p];
    if ((unsigned)n0 >= (unsigned)N_NODES) n0 = 0;
    if ((unsigned)n1 >= (unsigned)N_NODES) n1 = 0;
    if (t < 64) pv[t] = node[(size_t)n0 * 64 + t];
    else        pv[t] = node[(size_t)n1 * 64 + (t - 64)];
    __syncthreads();
    float s = fcb[t];
    #pragma unroll 4
    for (int k = 0; k < 128; ++k)
        s += pv[k] * fcW[k * 128 + t];
    out[(size_t)p * 128 + t] = tanhf(s);
}

extern "C" void kernel_launch(void* const* d_in, const int* in_sizes, int n_in,
                              void* d_out, int out_size, void* d_ws, size_t ws_size,
                              hipStream_t stream) {
    const float* x    = (const float*)d_in[0];
    const int* esrc   = (const int*)d_in[1];
    const int* edst   = (const int*)d_in[2];
    const int* etyp   = (const int*)d_in[3];
    // d_in[4] edge_attr: dead code in reference
    const int* nest   = (const int*)d_in[5];
    const int* food   = (const int*)d_in[6];
    const float* Wrel1  = (const float*)d_in[7];
    const float* Wroot1 = (const float*)d_in[8];
    const float* b1     = (const float*)d_in[9];
    const float* Wrel2  = (const float*)d_in[10];
    const float* Wroot2 = (const float*)d_in[11];
    const float* b2     = (const float*)d_in[12];
    const float* fcW    = (const float*)d_in[13];
    const float* fcb    = (const float*)d_in[14];
    float* out = (float*)d_out;

    // workspace layout (256B aligned chunks)
    char* ws = (char*)d_ws;
    size_t off = 0;
    auto alloc_b = [&](size_t bytes) -> void* {
        void* p = ws + off;
        off += (bytes + 255) & ~(size_t)255;
        return p;
    };
    int* cnt        = (int*)alloc_b((size_t)NSEG * 4);
    int* gcur       = (int*)alloc_b(4);
    int* seg_start  = (int*)alloc_b((size_t)NSEG * 4);
    int* seg_cur    = (int*)alloc_b((size_t)NSEG * 4);
    int* sorted_src = (int*)alloc_b((size_t)NEDGE * 4);
    u16* Wt1        = (u16*)alloc_b((size_t)128 * 512 * 2);
    u16* Wt2        = (u16*)alloc_b((size_t)64 * 512 * 2);
    u16* xb         = (u16*)alloc_b((size_t)N_NODES * 128 * 2);   // bf16(x)
    u16* Abuf       = (u16*)alloc_b((size_t)N_NODES * 384 * 2);   // bf16 agg
    u16* h1         = (u16*)alloc_b((size_t)N_NODES * 128 * 2);   // bf16
    float* node     = (float*)alloc_b((size_t)N_NODES * 64 * 4);  // f32

    zero_kernel<<<(NSEG + 255) / 256, 256, 0, stream>>>(cnt, gcur);

    // CSR build (shared by both layers)
    hist_kernel<<<NEDGE / 256, 256, 0, stream>>>(etyp, edst, cnt);
    alloc_seg<<<(NSEG / 4 + 255) / 256, 256, 0, stream>>>(cnt, seg_start, seg_cur, gcur);
    scatter_kernel<<<NEDGE / 256, 256, 0, stream>>>(esrc, edst, etyp, seg_cur, sorted_src);

    // weight transposes (f32 -> bf16 n-major)
    transpose_w<128><<<(128 * 512) / 256, 256, 0, stream>>>(Wrel1, Wroot1, Wt1);
    transpose_w<64><<<(64 * 512) / 256, 256, 0, stream>>>(Wrel2, Wroot2, Wt2);

    // cast x -> bf16
    cast_kernel<<<(N_NODES * 128 / 4 + 255) / 256, 256, 0, stream>>>(x, xb, N_NODES * 128 / 4);

    const int segBlocks  = (NSEG * 64) / 256;            // 75000
    const int gemmBlocks = (N_NODES + 127) / 128;        // 782

    // layer 1: agg(x) -> Abuf ; [Abuf|xb] @ Wt1 + b1, relu -> h1 (bf16)
    seg_mean<true><<<segBlocks, 256, 0, stream>>>(x, seg_start, cnt, sorted_src, Abuf);
    gemm_fused<128, true, false><<<gemmBlocks, 256, 0, stream>>>(Abuf, xb, Wt1, b1, h1);

    // layer 2: agg(h1) -> Abuf ; [Abuf|h1] @ Wt2 + b2 -> node (f32)
    seg_mean<false><<<segBlocks, 256, 0, stream>>>(h1, seg_start, cnt, sorted_src, Abuf);
    gemm_fused<64, false, true><<<gemmBlocks, 256, 0, stream>>>(Abuf, h1, Wt2, b2, node);

    // pair MLP (f32)
    pair_mlp<<<NPAIR, 128, 0, stream>>>(node, nest, food, fcW, fcb, out);
}

// Round 5
// 606.880 us; speedup vs baseline: 1.2604x; 1.2604x over previous
//
#include <hip/hip_runtime.h>
#include <stdint.h>

typedef unsigned short u16;
typedef __attribute__((ext_vector_type(8))) short short8;
typedef __attribute__((ext_vector_type(4))) float f32x4;

#define N_NODES 100000
#define RREL    3
#define NEDGE   1600000
#define NPAIR   1024
#define NSEG    (RREL * N_NODES)

// ---------- bf16 helpers ----------
__device__ __forceinline__ float bf2f(u16 h) {
    union { unsigned int u; float f; } c; c.u = ((unsigned int)h) << 16; return c.f;
}
__device__ __forceinline__ u16 f2bf(float f) {
    union { float f; unsigned int u; } c; c.f = f;
    unsigned int u = c.u;
    u += 0x7fffu + ((u >> 16) & 1u);   // round-to-nearest-even
    return (u16)(u >> 16);
}

// ---------- zero ints ----------
__global__ __launch_bounds__(256) void zero_kernel(int* __restrict__ cnt, int* __restrict__ gcur) {
    int i = blockIdx.x * 256 + threadIdx.x;
    if (i < NSEG) cnt[i] = 0;
    if (i == 0) *gcur = 0;
}

// ---------- cast f32 -> bf16, 4 elems/thread ----------
__global__ __launch_bounds__(256) void cast_kernel(const float* __restrict__ in,
                                                   u16* __restrict__ out, int n4) {
    int i = blockIdx.x * 256 + threadIdx.x;
    if (i >= n4) return;
    float4 v = ((const float4*)in)[i];
    uint2 o;
    o.x = ((unsigned int)f2bf(v.y) << 16) | (unsigned int)f2bf(v.x);
    o.y = ((unsigned int)f2bf(v.w) << 16) | (unsigned int)f2bf(v.z);
    ((uint2*)out)[i] = o;
}

// ---------- CSR build ----------
__global__ __launch_bounds__(256) void hist_kernel(const int* __restrict__ et,
                                                   const int* __restrict__ ed,
                                                   int* __restrict__ cnt) {
    int e = blockIdx.x * 256 + threadIdx.x;
    if (e < NEDGE) atomicAdd(&cnt[et[e] * N_NODES + ed[e]], 1);
}

// order-free contiguous slot allocation: wave-scan + one atomic per wave
__global__ __launch_bounds__(256) void alloc_seg(const int* __restrict__ cnt,
                                                 int* __restrict__ seg_start,
                                                 int* __restrict__ seg_cur,
                                                 int* __restrict__ gcur) {
    int t = blockIdx.x * 256 + threadIdx.x;   // handles 4 segments
    int i0 = t * 4;
    int c0 = 0, c1 = 0, c2 = 0, c3 = 0;
    if (i0 < NSEG) {
        const int4* c4 = (const int4*)cnt;
        int4 v = c4[t];
        c0 = v.x; c1 = v.y; c2 = v.z; c3 = v.w;
    }
    int s = c0 + c1 + c2 + c3;
    int pre = s;
    #pragma unroll
    for (int d = 1; d < 64; d <<= 1) {
        int v = __shfl_up(pre, d);
        if ((threadIdx.x & 63) >= d) pre += v;
    }
    int excl  = pre - s;
    int total = __shfl(pre, 63);
    int base  = 0;
    if ((threadIdx.x & 63) == 63) base = atomicAdd(gcur, total);
    base = __shfl(base, 63);
    if (i0 < NSEG) {
        int run = base + excl;
        seg_start[i0 + 0] = run; seg_cur[i0 + 0] = run; run += c0;
        seg_start[i0 + 1] = run; seg_cur[i0 + 1] = run; run += c1;
        seg_start[i0 + 2] = run; seg_cur[i0 + 2] = run; run += c2;
        seg_start[i0 + 3] = run; seg_cur[i0 + 3] = run;
    }
}

__global__ __launch_bounds__(256) void scatter_kernel(const int* __restrict__ es,
                                                      const int* __restrict__ ed,
                                                      const int* __restrict__ et,
                                                      int* __restrict__ seg_cur,
                                                      int* __restrict__ sorted_src) {
    int e = blockIdx.x * 256 + threadIdx.x;
    if (e < NEDGE) {
        int sgi = et[e] * N_NODES + ed[e];
        int p = atomicAdd(&seg_cur[sgi], 1);
        if ((unsigned)p < (unsigned)NEDGE) sorted_src[p] = es[e];
    }
}

// ---------- per-segment mean of bf16 (N,128) rows; one wave per (r,dst) ----------
// 4-way unrolled independent gathers for memory-level parallelism.
// writes Abuf as (N, 384) bf16: row dst, cols [r*128, r*128+128)
__global__ __launch_bounds__(256) void seg_mean(const unsigned int* __restrict__ Xu,  // (N,64) uint = bf16x2
                                                const int* __restrict__ seg_start,
                                                const int* __restrict__ cnt,
                                                const int* __restrict__ sorted_src,
                                                u16* __restrict__ Abuf) {
    int wid  = (blockIdx.x * 256 + threadIdx.x) >> 6;
    int lane = threadIdx.x & 63;
    if (wid >= NSEG) return;
    int r   = wid / N_NODES;
    int dst = wid - r * N_NODES;
    int c  = cnt[wid];
    int st = seg_start[wid];
    float a0 = 0.f, a1 = 0.f;
    int e = 0;
    for (; e + 4 <= c; e += 4) {
        int s0 = sorted_src[st + e + 0];
        int s1 = sorted_src[st + e + 1];
        int s2 = sorted_src[st + e + 2];
        int s3 = sorted_src[st + e + 3];
        unsigned int v0 = Xu[(size_t)s0 * 64 + lane];
        unsigned int v1 = Xu[(size_t)s1 * 64 + lane];
        unsigned int v2 = Xu[(size_t)s2 * 64 + lane];
        unsigned int v3 = Xu[(size_t)s3 * 64 + lane];
        a0 += bf2f((u16)(v0 & 0xffffu)) + bf2f((u16)(v1 & 0xffffu))
            + bf2f((u16)(v2 & 0xffffu)) + bf2f((u16)(v3 & 0xffffu));
        a1 += bf2f((u16)(v0 >> 16)) + bf2f((u16)(v1 >> 16))
            + bf2f((u16)(v2 >> 16)) + bf2f((u16)(v3 >> 16));
    }
    for (; e < c; ++e) {
        int src = sorted_src[st + e];
        unsigned int v = Xu[(size_t)src * 64 + lane];
        a0 += bf2f((u16)(v & 0xffffu));
        a1 += bf2f((u16)(v >> 16));
    }
    float sc = 1.0f / (float)(c > 0 ? c : 1);
    unsigned int o = ((unsigned int)f2bf(a1 * sc) << 16) | (unsigned int)f2bf(a0 * sc);
    ((unsigned int*)Abuf)[(size_t)dst * 192 + r * 64 + lane] = o;
}

// ---------- weight transpose: f32 (512 x BN) k-major -> bf16 Wt (BN x 512) n-major ----------
template <int BN>
__global__ __launch_bounds__(256) void transpose_w(const float* __restrict__ Wrel,
                                                   const float* __restrict__ Wroot,
                                                   u16* __restrict__ Wt) {
    int idx = blockIdx.x * 256 + threadIdx.x;
    if (idx >= BN * 512) return;
    int n = idx >> 9;
    int k = idx & 511;
    float v = (k < 384) ? Wrel[(size_t)k * BN + n] : Wroot[(size_t)(k - 384) * BN + n];
    Wt[idx] = f2bf(v);
}

// ---------- fused GEMM: Out(M,BN) = [Alo(M,384) | Ahi(M,128)]_bf16 @ Wt^T + bias ----------
template <int BN, bool RELU, bool OUTF32>
__global__ __launch_bounds__(256) void gemm_fused(const u16* __restrict__ Alo,
                                                  const u16* __restrict__ Ahi,
                                                  const u16* __restrict__ Wt,
                                                  const float* __restrict__ bias,
                                                  void* __restrict__ OutV) {
    constexpr int M = N_NODES;
    constexpr int BM = 128, BK = 32, KTOT = 512, KLO = 384;
    __shared__ __align__(16) u16 As[BM * BK];
    __shared__ __align__(16) u16 Bs[BN * BK];
    const int t = threadIdx.x;
    const int w = t >> 6, l = t & 63;
    const int bm = blockIdx.x * BM;
    constexpr int WN  = (BN == 128) ? 2 : 1;
    constexpr int WTM = (BN == 128) ? 64 : 32;
    constexpr int WTN = 64;
    constexpr int MI = WTM / 16, NI = WTN / 16;
    const int wm = w / WN, wn = w % WN;
    const int q = l >> 4, lm = l & 15;   // quad, intra-16 index

    f32x4 acc[MI][NI] = {};

    const int ar = t >> 2;            // 0..63
    const int ac = (t & 3) * 8;       // 0,8,16,24

    for (int kt = 0; kt < KTOT / BK; ++kt) {
        const int k0 = kt * BK;
        // ---- load tile into registers (global, 16B vector loads) ----
        const u16* base; int stride, kk;
        if (k0 < KLO) { base = Alo; stride = 384; kk = k0; }
        else          { base = Ahi; stride = 128; kk = k0 - KLO; }
        short8 va[2];
        #pragma unroll
        for (int i = 0; i < 2; ++i) {
            int gr = bm + i * 64 + ar; if (gr >= M) gr = M - 1;
            va[i] = *(const short8*)(base + (size_t)gr * stride + kk + ac);
        }
        short8 vb[BN / 64];
        #pragma unroll
        for (int i = 0; i < BN / 64; ++i) {
            int rn = i * 64 + ar;
            vb[i] = *(const short8*)(Wt + (size_t)rn * KTOT + k0 + ac);
        }
        // ---- store to LDS ----
        __syncthreads();   // previous iteration done reading LDS
        #pragma unroll
        for (int i = 0; i < 2; ++i)
            *(short8*)&As[(i * 64 + ar) * BK + ac] = va[i];
        #pragma unroll
        for (int i = 0; i < BN / 64; ++i)
            *(short8*)&Bs[(i * 64 + ar) * BK + ac] = vb[i];
        __syncthreads();
        // ---- one MFMA per (mi,ni) covers the whole K=32 tile ----
        // A-frag: lane holds A[m = lane&15][k = (lane>>4)*8 + j], j=0..7
        short8 fa[MI], fb[NI];
        #pragma unroll
        for (int mi = 0; mi < MI; ++mi)
            fa[mi] = *(const short8*)&As[(wm * WTM + mi * 16 + lm) * BK + q * 8];
        #pragma unroll
        for (int ni = 0; ni < NI; ++ni)
            fb[ni] = *(const short8*)&Bs[(wn * WTN + ni * 16 + lm) * BK + q * 8];
        #pragma unroll
        for (int mi = 0; mi < MI; ++mi)
            #pragma unroll
            for (int ni = 0; ni < NI; ++ni)
                acc[mi][ni] = __builtin_amdgcn_mfma_f32_16x16x32_bf16(
                    fa[mi], fb[ni], acc[mi][ni], 0, 0, 0);
    }
    // epilogue: C/D layout col=lane&15, row=q*4+reg
    #pragma unroll
    for (int mi = 0; mi < MI; ++mi) {
        #pragma unroll
        for (int ni = 0; ni < NI; ++ni) {
            int gc = wn * WTN + ni * 16 + lm;
            float bv = bias[gc];
            #pragma unroll
            for (int rg = 0; rg < 4; ++rg) {
                int gr = bm + wm * WTM + mi * 16 + q * 4 + rg;
                if (gr < M) {
                    float v = acc[mi][ni][rg] + bv;
                    if (RELU) v = fmaxf(v, 0.0f);
                    if (OUTF32) ((float*)OutV)[(size_t)gr * BN + gc] = v;
                    else        ((u16*)OutV)[(size_t)gr * BN + gc] = f2bf(v);
                }
            }
        }
    }
}

// ---------- final pair MLP: tanh(concat(node[nest],node[food]) @ fcW + fcb), all f32 ----------
__global__ __launch_bounds__(128) void pair_mlp(const float* __restrict__ node,
                                                const int* __restrict__ nest,
                                                const int* __restrict__ food,
                                                const float* __restrict__ fcW,
                                                const float* __restrict__ fcb,
                                                float* __restrict__ out) {
    int p = blockIdx.x;
    int t = threadIdx.x;
    __shared__ float pv[128];
    int n0 = nest[p], n1 = food[p];
    if ((unsigned)n0 >= (unsigned)N_NODES) n0 = 0;
    if ((unsigned)n1 >= (unsigned)N_NODES) n1 = 0;
    if (t < 64) pv[t] = node[(size_t)n0 * 64 + t];
    else        pv[t] = node[(size_t)n1 * 64 + (t - 64)];
    __syncthreads();
    float s = fcb[t];
    #pragma unroll 4
    for (int k = 0; k < 128; ++k)
        s += pv[k] * fcW[k * 128 + t];
    out[(size_t)p * 128 + t] = tanhf(s);
}

extern "C" void kernel_launch(void* const* d_in, const int* in_sizes, int n_in,
                              void* d_out, int out_size, void* d_ws, size_t ws_size,
                              hipStream_t stream) {
    const float* x    = (const float*)d_in[0];
    const int* esrc   = (const int*)d_in[1];
    const int* edst   = (const int*)d_in[2];
    const int* etyp   = (const int*)d_in[3];
    // d_in[4] edge_attr: dead code in reference
    const int* nest   = (const int*)d_in[5];
    const int* food   = (const int*)d_in[6];
    const float* Wrel1  = (const float*)d_in[7];
    const float* Wroot1 = (const float*)d_in[8];
    const float* b1     = (const float*)d_in[9];
    const float* Wrel2  = (const float*)d_in[10];
    const float* Wroot2 = (const float*)d_in[11];
    const float* b2     = (const float*)d_in[12];
    const float* fcW    = (const float*)d_in[13];
    const float* fcb    = (const float*)d_in[14];
    float* out = (float*)d_out;

    // workspace layout (256B aligned chunks)
    char* ws = (char*)d_ws;
    size_t off = 0;
    auto alloc_b = [&](size_t bytes) -> void* {
        void* p = ws + off;
        off += (bytes + 255) & ~(size_t)255;
        return p;
    };
    int* cnt        = (int*)alloc_b((size_t)NSEG * 4);
    int* gcur       = (int*)alloc_b(4);
    int* seg_start  = (int*)alloc_b((size_t)NSEG * 4);
    int* seg_cur    = (int*)alloc_b((size_t)NSEG * 4);
    int* sorted_src = (int*)alloc_b((size_t)NEDGE * 4);
    u16* Wt1        = (u16*)alloc_b((size_t)128 * 512 * 2);
    u16* Wt2        = (u16*)alloc_b((size_t)64 * 512 * 2);
    u16* xb         = (u16*)alloc_b((size_t)N_NODES * 128 * 2);   // bf16(x)
    u16* Abuf       = (u16*)alloc_b((size_t)N_NODES * 384 * 2);   // bf16 agg
    u16* h1         = (u16*)alloc_b((size_t)N_NODES * 128 * 2);   // bf16
    float* node     = (float*)alloc_b((size_t)N_NODES * 64 * 4);  // f32

    zero_kernel<<<(NSEG + 255) / 256, 256, 0, stream>>>(cnt, gcur);

    // CSR build (shared by both layers)
    hist_kernel<<<NEDGE / 256, 256, 0, stream>>>(etyp, edst, cnt);
    alloc_seg<<<(NSEG / 4 + 255) / 256, 256, 0, stream>>>(cnt, seg_start, seg_cur, gcur);
    scatter_kernel<<<NEDGE / 256, 256, 0, stream>>>(esrc, edst, etyp, seg_cur, sorted_src);

    // weight transposes (f32 -> bf16 n-major)
    transpose_w<128><<<(128 * 512) / 256, 256, 0, stream>>>(Wrel1, Wroot1, Wt1);
    transpose_w<64><<<(64 * 512) / 256, 256, 0, stream>>>(Wrel2, Wroot2, Wt2);

    // cast x -> bf16 (also the gather source for layer-1 aggregation)
    cast_kernel<<<(N_NODES * 128 / 4 + 255) / 256, 256, 0, stream>>>(x, xb, N_NODES * 128 / 4);

    const int segBlocks  = (NSEG * 64) / 256;            // 75000
    const int gemmBlocks = (N_NODES + 127) / 128;        // 782

    // layer 1: agg(xb) -> Abuf ; [Abuf|xb] @ Wt1 + b1, relu -> h1 (bf16)
    seg_mean<<<segBlocks, 256, 0, stream>>>((const unsigned int*)xb, seg_start, cnt, sorted_src, Abuf);
    gemm_fused<128, true, false><<<gemmBlocks, 256, 0, stream>>>(Abuf, xb, Wt1, b1, h1);

    // layer 2: agg(h1) -> Abuf ; [Abuf|h1] @ Wt2 + b2 -> node (f32)
    seg_mean<<<segBlocks, 256, 0, stream>>>((const unsigned int*)h1, seg_start, cnt, sorted_src, Abuf);
    gemm_fused<64, false, true><<<gemmBlocks, 256, 0, stream>>>(Abuf, h1, Wt2, b2, node);

    // pair MLP (f32)
    pair_mlp<<<NPAIR, 128, 0, stream>>>(node, nest, food, fcW, fcb, out);
}